// Round 5
// baseline (335.218 us; speedup 1.0000x reference)
//
#include <hip/hip_runtime.h>
#include <hip/hip_bf16.h>

// QuantizedLinear: out[64,11008] = x[64,4096] @ (Wq*scale)^T + bias
// R5: PF=4 deep register pipeline (24 loads in flight/wave) on the barrier-free
// wave-split-K structure. DUP=2 duplicates the whole GEMM grid (identical
// writes) as a DIAGNOSTIC so the dispatch exceeds the ~105us harness fills and
// shows up in rocprof top-5 if still slow. Remove DUP once diagnosed.

#define M_DIM 64
#define N_DIM 11008
#define K_DIM 4096
#define KC (K_DIM / 4)   // 1024 per wave (4 waves split K)
#define PF 4             // pipeline depth: iterations of loads in flight
#define DUP 2            // DIAGNOSTIC duplication factor

typedef __attribute__((ext_vector_type(8))) short bf16x8;
typedef __attribute__((ext_vector_type(4))) float f32x4;
typedef __attribute__((ext_vector_type(4))) int i32x4;
typedef __attribute__((ext_vector_type(8))) short s16x8;

// RNE float -> bf16
__device__ __forceinline__ short f2bf(float f) {
    unsigned int u = __builtin_bit_cast(unsigned int, f);
    u = u + 0x7FFFu + ((u >> 16) & 1u);
    return (short)(u >> 16);
}
// int in [-128,127] -> bf16 EXACT
__device__ __forceinline__ short i2bf(int q) {
    float f = (float)q;
    return (short)(__builtin_bit_cast(unsigned int, f) >> 16);
}
__device__ __forceinline__ bf16x8 cvt_w(i32x4 a, i32x4 b) {
    bf16x8 r;
    r[0] = i2bf(a.x); r[1] = i2bf(a.y); r[2] = i2bf(a.z); r[3] = i2bf(a.w);
    r[4] = i2bf(b.x); r[5] = i2bf(b.y); r[6] = i2bf(b.z); r[7] = i2bf(b.w);
    return r;
}

// ---- x [64][4096] f32 -> bf16 into ws ----
__global__ __launch_bounds__(256) void convert_x_kernel(const float* __restrict__ x,
                                                        short* __restrict__ xs) {
    int idx = blockIdx.x * 256 + threadIdx.x;   // 32768 threads x 8 elems
    const f32x4* p = (const f32x4*)x + (size_t)idx * 2;
    f32x4 a = p[0], b = p[1];
    s16x8 h;
    h[0] = f2bf(a.x); h[1] = f2bf(a.y); h[2] = f2bf(a.z); h[3] = f2bf(a.w);
    h[4] = f2bf(b.x); h[5] = f2bf(b.y); h[6] = f2bf(b.z); h[7] = f2bf(b.w);
    *((s16x8*)xs + idx) = h;
}

// ---- fused GEMM: tile M64 x N16; 4 waves split K; PF-deep pipeline ----
__global__ __launch_bounds__(256) void qgemm_kernel(const short* __restrict__ xs,
                                                    const int* __restrict__ wq,
                                                    const float* __restrict__ scale_p,
                                                    const float* __restrict__ bias,
                                                    float* __restrict__ out) {
    __shared__ float red[4][16][64];   // [wave][n][m], 16 KB

    const int t    = threadIdx.x;
    const int wv   = t >> 6;
    const int lane = t & 63;
    const int quad = lane >> 4;
    const int l16  = lane & 15;
    const int n0   = blockIdx.x * 16;   // blockIdx.y = DUP copy, ignored

    const int kbase = wv * KC;
    const int* wp = wq + (size_t)(n0 + l16) * K_DIM + kbase + quad * 8;
    const short* xp = xs + (size_t)l16 * K_DIM + kbase + quad * 8;

    f32x4 acc[4] = {f32x4{0,0,0,0}, f32x4{0,0,0,0}, f32x4{0,0,0,0}, f32x4{0,0,0,0}};

    // circular register buffers: PF iterations in flight
    i32x4  wb[PF][2];
    bf16x8 ab[PF][4];

    #pragma unroll
    for (int p = 0; p < PF; ++p) {
        wb[p][0] = *(const i32x4*)(wp + p * 32);
        wb[p][1] = *(const i32x4*)(wp + p * 32 + 4);
        #pragma unroll
        for (int mi = 0; mi < 4; ++mi)
            ab[p][mi] = *(const bf16x8*)(xp + (size_t)mi * 16 * K_DIM + p * 32);
    }

    // main loop: consume oldest slot, refill it PF iterations ahead
    #pragma unroll 4
    for (int kk = 0; kk < KC - PF * 32; kk += 32) {
        const int slot = (kk >> 5) & (PF - 1);
        bf16x8 bfrag = cvt_w(wb[slot][0], wb[slot][1]);
        #pragma unroll
        for (int mi = 0; mi < 4; ++mi)
            acc[mi] = __builtin_amdgcn_mfma_f32_16x16x32_bf16(ab[slot][mi], bfrag, acc[mi], 0, 0, 0);
        const int kn = kk + PF * 32;
        wb[slot][0] = *(const i32x4*)(wp + kn);
        wb[slot][1] = *(const i32x4*)(wp + kn + 4);
        #pragma unroll
        for (int mi = 0; mi < 4; ++mi)
            ab[slot][mi] = *(const bf16x8*)(xp + (size_t)mi * 16 * K_DIM + kn);
    }
    // drain the last PF slots
    #pragma unroll
    for (int p = 0; p < PF; ++p) {
        const int slot = (KC / 32 - PF + p) & (PF - 1);
        bf16x8 bfrag = cvt_w(wb[slot][0], wb[slot][1]);
        #pragma unroll
        for (int mi = 0; mi < 4; ++mi)
            acc[mi] = __builtin_amdgcn_mfma_f32_16x16x32_bf16(ab[slot][mi], bfrag, acc[mi], 0, 0, 0);
    }

    // ---- epilogue: cross-wave K reduction in LDS, fused scale+bias ----
    // C/D layout: D[m = quad*4 + r + 16*mi][n = l16] = acc[mi][r]
    #pragma unroll
    for (int mi = 0; mi < 4; ++mi)
        *(f32x4*)&red[wv][l16][mi * 16 + quad * 4] = acc[mi];
    __syncthreads();

    {
        const int n  = t & 15;
        const int mg = t >> 4;
        f32x4 s0 = *(const f32x4*)&red[0][n][mg * 4];
        f32x4 s1 = *(const f32x4*)&red[1][n][mg * 4];
        f32x4 s2 = *(const f32x4*)&red[2][n][mg * 4];
        f32x4 s3 = *(const f32x4*)&red[3][n][mg * 4];
        const float sc = *scale_p;
        const float b  = bias[n0 + n];
        #pragma unroll
        for (int j = 0; j < 4; ++j) {
            float v = (s0[j] + s1[j] + s2[j] + s3[j]) * sc + b;
            out[(size_t)(mg * 4 + j) * N_DIM + n0 + n] = v;
        }
    }
}

extern "C" void kernel_launch(void* const* d_in, const int* in_sizes, int n_in,
                              void* d_out, int out_size, void* d_ws, size_t ws_size,
                              hipStream_t stream) {
    const float* x     = (const float*)d_in[0];
    const int*   wq    = (const int*)d_in[1];
    const float* scale = (const float*)d_in[2];
    const float* bias  = (const float*)d_in[3];
    float* out = (float*)d_out;

    short* xs = (short*)d_ws;   // 512 KB bf16 copy of x

    convert_x_kernel<<<128, 256, 0, stream>>>(x, xs);

    // DUP copies do identical work and identical writes (benign duplicate
    // stores of identical values) — diagnostic only.
    dim3 grid(N_DIM / 16, DUP);
    qgemm_kernel<<<grid, 256, 0, stream>>>(xs, wq, scale, bias, out);
}

// Round 6
// 281.196 us; speedup vs baseline: 1.1921x; 1.1921x over previous
//
#include <hip/hip_runtime.h>
#include <hip/hip_bf16.h>

// QuantizedLinear: out[64,11008] = x[64,4096] @ (Wq*scale)^T + bias
// R6: memcpy-shaped weight staging. R5 counters showed FETCH ideal (184 MB)
// but HBM at 16%, all pipes idle -> the 16-row x 16KB-strided fine-grained
// access shape itself kills DRAM efficiency. Now each global_load_lds instr
// reads 1 KB contiguous of ONE row; each wave stages 4 consecutive rows
// (16 KB sequential). Waves split the staged K-range; x frags from L2.

#define M_DIM 64
#define N_DIM 11008
#define K_DIM 4096
#define KSPLIT 4
#define KC (K_DIM / KSPLIT)          // 1024 ints per row per block
#define OUT_ELEMS (M_DIM * N_DIM)    // 704512
#define ROWB 4112                    // LDS row stride: 4096 + 16 pad (16B-aligned)

typedef __attribute__((ext_vector_type(8))) short bf16x8;
typedef __attribute__((ext_vector_type(4))) float f32x4;
typedef __attribute__((ext_vector_type(4))) int i32x4;
typedef __attribute__((ext_vector_type(8))) short s16x8;

__device__ __forceinline__ short f2bf(float f) {          // RNE f32->bf16
    unsigned int u = __builtin_bit_cast(unsigned int, f);
    u = u + 0x7FFFu + ((u >> 16) & 1u);
    return (short)(u >> 16);
}
__device__ __forceinline__ short i2bf(int q) {            // exact for [-128,127]
    float f = (float)q;
    return (short)(__builtin_bit_cast(unsigned int, f) >> 16);
}
__device__ __forceinline__ bf16x8 cvt_w(i32x4 a, i32x4 b) {
    bf16x8 r;
    r[0] = i2bf(a.x); r[1] = i2bf(a.y); r[2] = i2bf(a.z); r[3] = i2bf(a.w);
    r[4] = i2bf(b.x); r[5] = i2bf(b.y); r[6] = i2bf(b.z); r[7] = i2bf(b.w);
    return r;
}

__device__ __forceinline__ void gload_lds(const void* g, void* l) {
    __builtin_amdgcn_global_load_lds(
        (const __attribute__((address_space(1))) unsigned int*)g,
        (__attribute__((address_space(3))) unsigned int*)l,
        16, 0, 0);
}

// ---- x [64][4096] f32 -> bf16 into ws ----
__global__ __launch_bounds__(256) void convert_x_kernel(const float* __restrict__ x,
                                                        short* __restrict__ xs) {
    int idx = blockIdx.x * 256 + threadIdx.x;   // 32768 threads x 8 elems
    const f32x4* p = (const f32x4*)x + (size_t)idx * 2;
    f32x4 a = p[0], b = p[1];
    s16x8 h;
    h[0] = f2bf(a.x); h[1] = f2bf(a.y); h[2] = f2bf(a.z); h[3] = f2bf(a.w);
    h[4] = f2bf(b.x); h[5] = f2bf(b.y); h[6] = f2bf(b.z); h[7] = f2bf(b.w);
    *((s16x8*)xs + idx) = h;
}

// ---- GEMM: grid (688, KSPLIT); block 256 thr; tile M64 x N16 ----
__global__ __launch_bounds__(256) void qgemm_kernel(const short* __restrict__ xs,
                                                    const int* __restrict__ wq,
                                                    float* __restrict__ part) {
    __shared__ __align__(16) char smem[16 * ROWB];   // 65792 B -> 2 blocks/CU

    const int t    = threadIdx.x;
    const int wv   = t >> 6;
    const int lane = t & 63;
    const int quad = lane >> 4;
    const int l16  = lane & 15;
    const int n0   = blockIdx.x * 16;
    const int ks   = blockIdx.y;
    const int k0   = ks * KC;

    // ---- stage: wave wv copies rows wv*4..wv*4+3, 1 KB contiguous per instr ----
    {
        #pragma unroll
        for (int rr = 0; rr < 4; ++rr) {
            const int r = wv * 4 + rr;
            const int* src = wq + (size_t)(n0 + r) * K_DIM + k0 + lane * 4;
            char* dst = smem + r * ROWB + lane * 16;
            #pragma unroll
            for (int i = 0; i < 4; ++i)
                gload_lds(src + i * 256, dst + i * 1024);   // 1 KB contiguous each
        }
    }
    __syncthreads();   // drains the LDS-DMA (compiler emits vmcnt(0))

    // ---- consume: wave wv takes k-subrange [wv*256, wv*256+256) ----
    f32x4 acc[4] = {f32x4{0,0,0,0}, f32x4{0,0,0,0}, f32x4{0,0,0,0}, f32x4{0,0,0,0}};

    const char* wrow = smem + l16 * ROWB;                 // this lane's weight row
    const int   ko   = wv * 256 + quad * 8;               // int offset in buffer
    const short* xp  = xs + (size_t)l16 * K_DIM + k0 + ko;

    #pragma unroll
    for (int kk = 0; kk < 256; kk += 32) {
        i32x4 w0 = *(const i32x4*)(wrow + (ko + kk) * 4);
        i32x4 w1 = *(const i32x4*)(wrow + (ko + kk + 4) * 4);
        bf16x8 bfrag = cvt_w(w0, w1);
        #pragma unroll
        for (int mi = 0; mi < 4; ++mi) {
            bf16x8 afrag = *(const bf16x8*)(xp + (size_t)mi * 16 * K_DIM + kk);
            acc[mi] = __builtin_amdgcn_mfma_f32_16x16x32_bf16(afrag, bfrag, acc[mi], 0, 0, 0);
        }
    }
    __syncthreads();   // LDS reads done; smem now reusable for reduction

    // ---- epilogue: cross-wave K reduction in LDS (reuse smem) ----
    // C/D layout: D[m = quad*4 + r + 16*mi][n = l16] = acc[mi][r]
    float (*red)[16][64] = (float (*)[16][64])smem;       // [wave][n][m], 16 KB
    #pragma unroll
    for (int mi = 0; mi < 4; ++mi)
        *(f32x4*)&red[wv][l16][mi * 16 + quad * 4] = acc[mi];
    __syncthreads();

    {
        const int n  = t & 15;
        const int mg = t >> 4;
        f32x4 s0 = *(const f32x4*)&red[0][n][mg * 4];
        f32x4 s1 = *(const f32x4*)&red[1][n][mg * 4];
        f32x4 s2 = *(const f32x4*)&red[2][n][mg * 4];
        f32x4 s3 = *(const f32x4*)&red[3][n][mg * 4];
        float* ps = part + (size_t)ks * OUT_ELEMS + n0 + n;
        #pragma unroll
        for (int j = 0; j < 4; ++j)
            ps[(size_t)(mg * 4 + j) * N_DIM] = s0[j] + s1[j] + s2[j] + s3[j];
    }
}

// ---- out = scale * sum_s part[s] + bias ----
__global__ __launch_bounds__(256) void reduce_kernel(const float* __restrict__ part,
                                                     const float* __restrict__ scale_p,
                                                     const float* __restrict__ bias,
                                                     float* __restrict__ out) {
    int i4 = blockIdx.x * 256 + threadIdx.x;     // 176128 f32x4
    float s = *scale_p;
    int col4 = i4 % 2752;                        // N/4
    f32x4 b = *(const f32x4*)(bias + col4 * 4);
    f32x4 a = *((const f32x4*)part + i4);
    #pragma unroll
    for (int sl = 1; sl < KSPLIT; ++sl) {
        f32x4 c = *((const f32x4*)(part + (size_t)sl * OUT_ELEMS) + i4);
        a.x += c.x; a.y += c.y; a.z += c.z; a.w += c.w;
    }
    f32x4 r;
    r.x = a.x * s + b.x; r.y = a.y * s + b.y;
    r.z = a.z * s + b.z; r.w = a.w * s + b.w;
    *((f32x4*)out + i4) = r;
}

extern "C" void kernel_launch(void* const* d_in, const int* in_sizes, int n_in,
                              void* d_out, int out_size, void* d_ws, size_t ws_size,
                              hipStream_t stream) {
    const float* x     = (const float*)d_in[0];
    const int*   wq    = (const int*)d_in[1];
    const float* scale = (const float*)d_in[2];
    const float* bias  = (const float*)d_in[3];
    float* out = (float*)d_out;

    float* part = (float*)d_ws;                                            // 11.3 MB
    short* xs   = (short*)((char*)d_ws + (size_t)KSPLIT * OUT_ELEMS * 4);  // 512 KB

    convert_x_kernel<<<128, 256, 0, stream>>>(x, xs);

    dim3 grid(N_DIM / 16, KSPLIT);   // (688, 4)
    qgemm_kernel<<<grid, 256, 0, stream>>>(xs, wq, part);

    reduce_kernel<<<688, 256, 0, stream>>>(part, scale, bias, out);
}